// Round 2
// baseline (208357.153 us; speedup 1.0000x reference)
//
#include <hip/hip_runtime.h>
#include <hip/hip_bf16.h>

#define DEV_INLINE __device__ __forceinline__

typedef __attribute__((ext_vector_type(8))) short bf16x8;
typedef __attribute__((ext_vector_type(4))) float f32x4;

// Problem constants
constexpr int Bc = 64, Sc = 512, Dc = 512, Hc = 8, HDc = 64, MELc = 80, Tc = 2560;
constexpr int OUTSTRIDE = Tc * MELc; // 204800

// ---------------- workspace layout (bytes) ----------------
constexpr size_t SZ_KP  = 64ull * 8 * 512 * 64 * 2;     // 33554432 bf16 K[b][h][s][d]
constexpr size_t SZ_PL  = 128ull * 2048 * 16;           // 4194304  packed LSTM cell
constexpr size_t OFF_KP  = 0;
constexpr size_t OFF_VP  = OFF_KP + SZ_KP;
constexpr size_t OFF_PL0 = OFF_VP + SZ_KP;
constexpr size_t OFF_PL1 = OFF_PL0 + SZ_PL;
constexpr size_t OFF_PL2 = OFF_PL1 + SZ_PL;
constexpr size_t OFF_PWQ = OFF_PL2 + SZ_PL;             // 524288
constexpr size_t OFF_PP  = OFF_PWQ + 524288;            // 81920
constexpr size_t OFF_BL0 = OFF_PP + 81920;              // 8192
constexpr size_t OFF_BL1 = OFF_BL0 + 8192;
constexpr size_t OFF_BL2 = OFF_BL1 + 8192;
constexpr size_t OFF_B2E = OFF_BL2 + 8192;              // 8192 (f32 2048)
constexpr size_t OFF_W2E = OFF_B2E + 8192;              // 2097152 (bf16 2048x512)
constexpr size_t OFF_WOT = OFF_W2E + 2097152;           // 1048576 (f32 512x512)
constexpr size_t OFF_ACT = OFF_WOT + 1048576;           // 524288: h10[2],h11[2],h2[2],ctx[2]
constexpr size_t OFF_FLG = OFF_ACT + 524288;            // 4096

// ---------------- helpers ----------------
DEV_INLINE float bf2f(short s) { return __uint_as_float(((unsigned)(unsigned short)s) << 16); }
DEV_INLINE short f2bf(float f) { union { __hip_bfloat16 h; short s; } u; u.h = __float2bfloat16(f); return u.s; }
DEV_INLINE float sig_f(float x) { return 1.0f / (1.0f + __expf(-x)); }
DEV_INLINE float tanh_f(float x) {
  float ax = fabsf(x);
  float e = __expf(fminf(2.0f * ax, 80.0f));
  float r = 1.0f - 2.0f / (e + 1.0f);
  return copysignf(r, x);
}
DEV_INLINE bf16x8 cvt8(const float* p) {
  bf16x8 r;
#pragma unroll
  for (int i = 0; i < 8; ++i) r[i] = f2bf(p[i]);
  return r;
}

// ---------------- setup kernels ----------------

// out = A[M,512] @ Bt[N=512-block rows][512].T  (bf16 MFMA, fp32 in)
// mode 0: KV pack dst[((b*8+h)*512+s)*64+d] with bias[n]; mode 1: row-major bf16 [M,512]
__global__ __launch_bounds__(256) void gemm_setup(const float* __restrict__ A,
                                                  const float* __restrict__ Bt,
                                                  const float* __restrict__ bias,
                                                  __hip_bfloat16* __restrict__ dst,
                                                  int mode) {
  int tid = threadIdx.x, lane = tid & 63, wv = tid >> 6;
  int m0 = blockIdx.y * 64 + wv * 16;
  int nb = blockIdx.x * 64;
  int mrow = m0 + (lane & 15);
  int kb = (lane >> 4) * 8;
  f32x4 acc0 = {0,0,0,0}, acc1 = {0,0,0,0}, acc2 = {0,0,0,0}, acc3 = {0,0,0,0};
  const float* arow = A + (size_t)mrow * 512 + kb;
  const float* b0r = Bt + (size_t)(nb + 0 * 16 + (lane & 15)) * 512 + kb;
  const float* b1r = Bt + (size_t)(nb + 1 * 16 + (lane & 15)) * 512 + kb;
  const float* b2r = Bt + (size_t)(nb + 2 * 16 + (lane & 15)) * 512 + kb;
  const float* b3r = Bt + (size_t)(nb + 3 * 16 + (lane & 15)) * 512 + kb;
  for (int kk = 0; kk < 16; ++kk) {
    bf16x8 af = cvt8(arow + kk * 32);
    acc0 = __builtin_amdgcn_mfma_f32_16x16x32_bf16(af, cvt8(b0r + kk * 32), acc0, 0, 0, 0);
    acc1 = __builtin_amdgcn_mfma_f32_16x16x32_bf16(af, cvt8(b1r + kk * 32), acc1, 0, 0, 0);
    acc2 = __builtin_amdgcn_mfma_f32_16x16x32_bf16(af, cvt8(b2r + kk * 32), acc2, 0, 0, 0);
    acc3 = __builtin_amdgcn_mfma_f32_16x16x32_bf16(af, cvt8(b3r + kk * 32), acc3, 0, 0, 0);
  }
  int col16 = lane & 15, r0 = (lane >> 4) * 4;
  f32x4 accs[4] = {acc0, acc1, acc2, acc3};
#pragma unroll
  for (int nt = 0; nt < 4; ++nt) {
    int n = nb + nt * 16 + col16;
#pragma unroll
    for (int r = 0; r < 4; ++r) {
      int m = m0 + r0 + r;
      float v = accs[nt][r];
      if (mode == 0) {
        v += bias[n];
        int bb = m >> 9, s = m & 511, h = n >> 6, d = n & 63;
        dst[(((size_t)(bb * 8 + h) * 512 + s) * 64) + d] = __float2bfloat16(v);
      } else {
        dst[(size_t)m * 512 + n] = __float2bfloat16(v);
      }
    }
  }
}

__global__ __launch_bounds__(256) void transpose512(const float* __restrict__ in, float* __restrict__ out) {
  __shared__ float tl[32][33];
  int x = threadIdx.x & 31, ty = threadIdx.x >> 5;
  int bx = blockIdx.x * 32, by = blockIdx.y * 32;
#pragma unroll
  for (int r = 0; r < 4; ++r) tl[ty + r * 8][x] = in[(size_t)(by + ty + r * 8) * 512 + bx + x];
  __syncthreads();
#pragma unroll
  for (int r = 0; r < 4; ++r) out[(size_t)(bx + ty + r * 8) * 512 + by + x] = tl[x][ty + r * 8];
}

__global__ __launch_bounds__(256) void b2eff_k(const float* __restrict__ w2ih, const float* __restrict__ bout,
                                               const float* __restrict__ bih, const float* __restrict__ bhh,
                                               float* __restrict__ dst) {
  int g = blockIdx.x * 256 + threadIdx.x;
  float acc = bih[g] + bhh[g];
  const float* row = w2ih + (size_t)g * 512;
  for (int k = 0; k < 512; ++k) acc += row[k] * bout[k];
  dst[g] = acc;
}

// Pack one LSTM cell: rows reordered (i0..3,f0..3,g0..3,o0..3 per 4-unit slice), K-cat = [lo(512)|hi(512)]
// mode 0: lo = f32 w_ih, bias = b1+b2 ; mode 1: lo = bf16 (W2eff), bias = b_pre
__global__ __launch_bounds__(256) void pack_lstm(const float* __restrict__ lo_f32,
                                                 const __hip_bfloat16* __restrict__ lo_bf16,
                                                 const float* __restrict__ hi_f32,
                                                 const float* __restrict__ b1, const float* __restrict__ b2,
                                                 const float* __restrict__ b_pre,
                                                 __hip_bfloat16* __restrict__ dst, float* __restrict__ bias_out,
                                                 int mode) {
  int u = blockIdx.x, tid = threadIdx.x;
  for (int rep = 0; rep < 8; ++rep) {
    int slot = rep * 256 + tid;            // 0..2047
    int kk = slot >> 6, lane = slot & 63;
    int n16 = lane & 15, gate = n16 >> 2, jj = n16 & 3;
    int srow = gate * 512 + u * 4 + jj;
    int k = kk * 32 + (lane >> 4) * 8;
    __hip_bfloat16 tmp[8];
    if (k < 512) {
      if (mode == 0) {
#pragma unroll
        for (int i = 0; i < 8; ++i) tmp[i] = __float2bfloat16(lo_f32[(size_t)srow * 512 + k + i]);
      } else {
#pragma unroll
        for (int i = 0; i < 8; ++i) tmp[i] = lo_bf16[(size_t)srow * 512 + k + i];
      }
    } else {
#pragma unroll
      for (int i = 0; i < 8; ++i) tmp[i] = __float2bfloat16(hi_f32[(size_t)srow * 512 + (k - 512) + i]);
    }
    *(uint4*)(dst + ((size_t)u * 2048 + slot) * 8) = *(uint4*)tmp;
  }
  if (tid < 16) {
    int gate = tid >> 2, jj = tid & 3;
    int srow = gate * 512 + u * 4 + jj;
    bias_out[u * 16 + tid] = (mode == 0) ? (b1[srow] + b2[srow]) : b_pre[srow];
  }
}

__global__ __launch_bounds__(256) void pack_wq(const float* __restrict__ wq, __hip_bfloat16* __restrict__ dst) {
  int h = blockIdx.x, tid = threadIdx.x;
  for (int rep = 0; rep < 16; ++rep) {
    int slot = rep * 256 + tid;            // 0..4095: nt*1024 + kk*64 + lane
    int nt = slot >> 10, kk = (slot >> 6) & 15, lane = slot & 63;
    int srow = h * 64 + nt * 16 + (lane & 15);
    int k = kk * 32 + (lane >> 4) * 8;
    __hip_bfloat16 tmp[8];
#pragma unroll
    for (int i = 0; i < 8; ++i) tmp[i] = __float2bfloat16(wq[(size_t)srow * 512 + k + i]);
    *(uint4*)(dst + ((size_t)h * 4096 + slot) * 8) = *(uint4*)tmp;
  }
}

__global__ __launch_bounds__(256) void pack_proj(const float* __restrict__ pw, __hip_bfloat16* __restrict__ dst) {
  int u5 = blockIdx.x, tid = threadIdx.x;
  for (int rep = 0; rep < 4; ++rep) {
    int slot = rep * 256 + tid;            // 0..1023: kk*64 + lane
    int kk = slot >> 6, lane = slot & 63;
    int srow = u5 * 16 + (lane & 15);
    int k = kk * 32 + (lane >> 4) * 8;
    __hip_bfloat16 tmp[8];
#pragma unroll
    for (int i = 0; i < 8; ++i) tmp[i] = __float2bfloat16(pw[(size_t)srow * 512 + k + i]);
    *(uint4*)(dst + ((size_t)u5 * 1024 + slot) * 8) = *(uint4*)tmp;
  }
}

// ---------------- main persistent decoder ----------------
struct DecParams {
  const float* attn_in_b;
  const float* proj_b;
  const uint4* packL0; const uint4* packL1; const uint4* packL2;
  const float* biasL0; const float* biasL1; const float* biasL2;
  const uint4* packWq; const uint4* packP;
  const __hip_bfloat16* Kp; const __hip_bfloat16* Vp;
  __hip_bfloat16* h10b; __hip_bfloat16* h11b; __hip_bfloat16* h2b; __hip_bfloat16* ctxb;
  uint4* actbase;
  unsigned* flags;
  float* out;
};

constexpr unsigned long long WD_TICKS = 200000000ull;   // watchdog: ~2-8 s of s_memrealtime

DEV_INLINE void publish_flag(unsigned* flags, int wg, unsigned id, int tid) {
  __syncthreads();  // all waves' prior stores issued
  if (tid == 0)
    __hip_atomic_store(&flags[wg], id, __ATOMIC_RELEASE, __HIP_MEMORY_SCOPE_AGENT);
}

// returns false on watchdog timeout (block-uniform)
DEV_INLINE bool wait_flags(unsigned* flags, int base, int count, unsigned id, int tid,
                           unsigned long long t0, int* bail) {
  if (tid < 64) {
    for (;;) {
      bool ok = true;
      for (int i = tid; i < count; i += 64)
        ok &= (__hip_atomic_load(&flags[base + i], __ATOMIC_RELAXED, __HIP_MEMORY_SCOPE_AGENT) >= id);
      if (__all(ok ? 1 : 0)) break;
      if (__builtin_amdgcn_s_memrealtime() - t0 > WD_TICKS) { if (tid == 0) *bail = 1; break; }
      __builtin_amdgcn_s_sleep(2);
    }
  }
  __syncthreads();
  if (*bail) return false;
  // per-thread acquire: orders subsequent data loads, invalidates stale caches
  (void)__hip_atomic_load(&flags[0], __ATOMIC_ACQUIRE, __HIP_MEMORY_SCOPE_AGENT);
  return true;
}

// One LSTM slice: gates[64,16] = [actLo|actHi][64,1024] @ Wslice.T  → h,c for 4 units
DEV_INLINE void lstm_slice(int tid, const uint4* packW, const float* bias,
                           const __hip_bfloat16* actLo, const __hip_bfloat16* actHi,
                           float* c_lds, __hip_bfloat16* hout, float* gates) {
  int lane = tid & 63, wv = tid >> 6;
  int m = wv * 16 + (lane & 15);
  int kb = (lane >> 4) * 8;
  f32x4 acc = {0,0,0,0};
  const __hip_bfloat16* pLo = actLo + (size_t)m * 512 + kb;
  const __hip_bfloat16* pHi = actHi + (size_t)m * 512 + kb;
#pragma unroll 8
  for (int kk = 0; kk < 32; ++kk) {
    const __hip_bfloat16* src = (kk < 16) ? (pLo + kk * 32) : (pHi + kk * 32 - 512);
    bf16x8 a = *(const bf16x8*)src;
    bf16x8 b = *(const bf16x8*)(packW + kk * 64 + lane);
    acc = __builtin_amdgcn_mfma_f32_16x16x32_bf16(a, b, acc, 0, 0, 0);
  }
  int row0 = wv * 16 + ((lane >> 4) << 2), col = lane & 15;
#pragma unroll
  for (int r = 0; r < 4; ++r) gates[(row0 + r) * 17 + col] = acc[r];
  __syncthreads();
  int bb = tid >> 2, j = tid & 3;
  float gi = gates[bb * 17 + j]      + bias[j];
  float gf = gates[bb * 17 + 4 + j]  + bias[4 + j];
  float gg = gates[bb * 17 + 8 + j]  + bias[8 + j];
  float go = gates[bb * 17 + 12 + j] + bias[12 + j];
  float c = c_lds[tid];
  c = sig_f(gf) * c + sig_f(gi) * tanh_f(gg);
  float h = sig_f(go) * tanh_f(c);
  c_lds[tid] = c;
  hout[bb * 512 + j] = __float2bfloat16(h);
}

DEV_INLINE void proj_slice(int tid, const uint4* packW, const float* bias,
                           const __hip_bfloat16* actLo, float* outp, int u5) {
  int lane = tid & 63, wv = tid >> 6;
  int m = wv * 16 + (lane & 15);
  int kb = (lane >> 4) * 8;
  f32x4 acc = {0,0,0,0};
  const __hip_bfloat16* pA = actLo + (size_t)m * 512 + kb;
#pragma unroll 8
  for (int kk = 0; kk < 16; ++kk) {
    bf16x8 a = *(const bf16x8*)(pA + kk * 32);
    bf16x8 b = *(const bf16x8*)(packW + kk * 64 + lane);
    acc = __builtin_amdgcn_mfma_f32_16x16x32_bf16(a, b, acc, 0, 0, 0);
  }
  int col = lane & 15, row0 = wv * 16 + ((lane >> 4) << 2);
  float bia = bias[u5 * 16 + col];
#pragma unroll
  for (int r = 0; r < 4; ++r)
    outp[(size_t)(row0 + r) * OUTSTRIDE + u5 * 16 + col] = acc[r] + bia;
}

__global__ __launch_bounds__(256, 1) void decoder_main(DecParams P) {
  const int wg = blockIdx.x, tid = threadIdx.x;
  const int lane = tid & 63, wv = tid >> 6;
  __shared__ float gates[64 * 17];
  __shared__ float qls[16 * 68];
  __shared__ float sco[2 * 512];
  __shared__ float red[2 * 16 * 64];
  __shared__ float cA[256], cB[256];
  __shared__ float smx[4], ssum[4], sinv[2];
  __shared__ int s_bail;

  const unsigned long long t0 = __builtin_amdgcn_s_memrealtime();
  const int hh = wg >> 5;
  const int b0 = (wg & 31) * 2;
  const int bblk = b0 & ~15;
  const uint4* myL0 = P.packL0 + (size_t)wg * 2048;
  const uint4* myL1 = P.packL1 + (size_t)(wg - 128) * 2048;
  const uint4* myL2 = P.packL2 + (size_t)wg * 2048;
  const uint4* myWq = P.packWq + (size_t)hh * 4096;

  if (tid == 0) s_bail = 0;
  cA[tid] = 0.0f; cB[tid] = 0.0f;

  // zero activation buffers (512 KB total, 128 uint4 per WG)
  if (tid < 128) { uint4 z{0u, 0u, 0u, 0u}; P.actbase[wg * 128 + tid] = z; }
  publish_flag(P.flags, wg, 1u, tid);
  // pre-loop global barrier: everyone's zeroing visible before first reads
  if (!wait_flags(P.flags, 0, 256, 1u, tid, t0, &s_bail)) goto bail;

  for (int t = 0; t < Tc; ++t) {
    const int cur = t & 1, pv = cur ^ 1;
    const unsigned idA = 4u * t + 1, idApub = 4u * t + 2, idBpub = 4u * t + 3,
                   idCpub = 4u * t + 4, idDpub = 4u * t + 5;
    __hip_bfloat16* h10c = P.h10b + cur * 32768; __hip_bfloat16* h10p = P.h10b + pv * 32768;
    __hip_bfloat16* h11c = P.h11b + cur * 32768; __hip_bfloat16* h11p = P.h11b + pv * 32768;
    __hip_bfloat16* h2c  = P.h2b  + cur * 32768; __hip_bfloat16* h2p  = P.h2b  + pv * 32768;
    __hip_bfloat16* ctxc = P.ctxb + cur * 32768;

    if (wg < 128) {
      // ---- stage A: LSTM0 ----
      if (!wait_flags(P.flags, 0, 128, idA, tid, t0, &s_bail)) goto bail;
      lstm_slice(tid, myL0, P.biasL0 + wg * 16, h2p, h10p, cA, h10c + wg * 4, gates);
      publish_flag(P.flags, wg, idApub, tid);
    } else {
      if (wg < 133 && t > 0) {
        if (!wait_flags(P.flags, 0, 128, idA, tid, t0, &s_bail)) goto bail;
        proj_slice(tid, P.packP + (size_t)(wg - 128) * 1024, P.proj_b, h2p,
                   P.out + (size_t)(t - 1) * MELc, wg - 128);
      }
      // ---- stage B: LSTM1 ----
      if (!wait_flags(P.flags, 0, 128, idApub, tid, t0, &s_bail)) goto bail;
      lstm_slice(tid, myL1, P.biasL1 + (wg - 128) * 16, h10c, h11p, cA, h11c + (wg - 128) * 4, gates);
      publish_flag(P.flags, wg, idBpub, tid);
    }

    // ---- stage C: attention (all WGs, 2 (b,h) pairs each) ----
    if (!wait_flags(P.flags, 128, 128, idBpub, tid, t0, &s_bail)) goto bail;
    {
      // q = (h11 @ Wq[h].T + bq) * 0.125  via MFMA over 16 batch rows
      int m = bblk + (lane & 15);
      int kb2 = (lane >> 4) * 8;
      f32x4 acc = {0,0,0,0};
      const __hip_bfloat16* pA = h11c + (size_t)m * 512 + kb2;
      const uint4* pB = myWq + wv * 1024;
#pragma unroll 8
      for (int kk = 0; kk < 16; ++kk) {
        bf16x8 a = *(const bf16x8*)(pA + kk * 32);
        bf16x8 b = *(const bf16x8*)(pB + kk * 64 + lane);
        acc = __builtin_amdgcn_mfma_f32_16x16x32_bf16(a, b, acc, 0, 0, 0);
      }
      int col = lane & 15, row0 = (lane >> 4) << 2;
      int dg = wv * 16 + col;
      float bq = P.attn_in_b[hh * 64 + dg];
#pragma unroll
      for (int r = 0; r < 4; ++r) qls[(row0 + r) * 68 + dg] = (acc[r] + bq) * 0.125f;
    }
    __syncthreads();
    {
      // scores: 2 pairs x 512 positions, 4 per thread
      int p = tid >> 7, si = tid & 127;
      int bb = b0 + p;
      int qrow = (b0 & 15) + p;
      const float* qv = qls + qrow * 68;
      const __hip_bfloat16* Kb = P.Kp + ((size_t)(bb * 8 + hh) * 512) * 64;
#pragma unroll
      for (int ss = 0; ss < 4; ++ss) {
        int s = si * 4 + ss;
        const bf16x8* kr = (const bf16x8*)(Kb + (size_t)s * 64);
        float acc = 0.0f;
#pragma unroll
        for (int i = 0; i < 8; ++i) {
          bf16x8 kvv = kr[i];
#pragma unroll
          for (int jj = 0; jj < 8; ++jj) acc += qv[i * 8 + jj] * bf2f(kvv[jj]);
        }
        sco[p * 512 + s] = acc;
      }
    }
    __syncthreads();
    {
      // softmax (unnormalized exp in LDS + 1/sum)
      int p = wv >> 1, half = wv & 1;
      int idx = tid & 127;
      float mx = -1e30f;
#pragma unroll
      for (int ss = 0; ss < 4; ++ss) mx = fmaxf(mx, sco[p * 512 + idx * 4 + ss]);
#pragma unroll
      for (int off = 32; off; off >>= 1) mx = fmaxf(mx, __shfl_xor(mx, off));
      if (lane == 0) smx[p * 2 + half] = mx;
      __syncthreads();
      float m = fmaxf(smx[p * 2], smx[p * 2 + 1]);
      float sum = 0.0f;
#pragma unroll
      for (int ss = 0; ss < 4; ++ss) {
        int ix = p * 512 + idx * 4 + ss;
        float e = __expf(sco[ix] - m);
        sco[ix] = e; sum += e;
      }
#pragma unroll
      for (int off = 32; off; off >>= 1) sum += __shfl_xor(sum, off);
      if (lane == 0) ssum[p * 2 + half] = sum;
      __syncthreads();
      if (tid < 2) sinv[tid] = 1.0f / (ssum[tid * 2] + ssum[tid * 2 + 1]);
    }
    __syncthreads();
    {
      // ctx = p . V   (per pair: 2 waves split s-range; lane = (sg, dj))
      int p = wv >> 1, half = wv & 1;
      int bb = b0 + p;
      int sg = lane >> 3, dj = lane & 7;
      const __hip_bfloat16* Vb = P.Vp + ((size_t)(bb * 8 + hh) * 512) * 64;
      float a8[8] = {0,0,0,0,0,0,0,0};
      for (int it = 0; it < 32; ++it) {
        int s = half * 256 + it * 8 + sg;
        float w = sco[p * 512 + s];
        bf16x8 v = *(const bf16x8*)(Vb + (size_t)s * 64 + dj * 8);
#pragma unroll
        for (int e = 0; e < 8; ++e) a8[e] += w * bf2f(v[e]);
      }
      float* rp = red + ((p * 16 + half * 8 + sg) * 64) + dj * 8;
#pragma unroll
      for (int e = 0; e < 8; ++e) rp[e] = a8[e];
    }
    __syncthreads();
    if (tid < 128) {
      int p = tid >> 6, d = tid & 63;
      float sacc = 0.0f;
#pragma unroll
      for (int k = 0; k < 16; ++k) sacc += red[(p * 16 + k) * 64 + d];
      sacc *= sinv[p];
      ctxc[(size_t)(b0 + p) * 512 + hh * 64 + d] = __float2bfloat16(sacc);
    }
    publish_flag(P.flags, wg, idCpub, tid);

    if (wg < 128) {
      // ---- stage D: LSTM2 (out-proj folded into W2eff) ----
      if (!wait_flags(P.flags, 0, 256, idCpub, tid, t0, &s_bail)) goto bail;
      lstm_slice(tid, myL2, P.biasL2 + wg * 16, ctxc, h2p, cB, h2c + wg * 4, gates);
      publish_flag(P.flags, wg, idDpub, tid);
    }
  }

  // final projection for t = T-1
  if (wg >= 128 && wg < 133) {
    if (wait_flags(P.flags, 0, 128, 4u * (Tc - 1) + 5, tid, t0, &s_bail))
      proj_slice(tid, P.packP + (size_t)(wg - 128) * 1024, P.proj_b,
                 P.h2b + ((Tc - 1) & 1) * 32768, P.out + (size_t)(Tc - 1) * MELc, wg - 128);
  }
  return;

bail:
  // watchdog fired: unblock peers and exit (wrong output, but no hang)
  publish_flag(P.flags, wg, 0x7F000000u, tid);
}

// ---------------- launcher ----------------
extern "C" void kernel_launch(void* const* d_in, const int* in_sizes, int n_in,
                              void* d_out, int out_size, void* d_ws, size_t ws_size,
                              hipStream_t stream) {
  const float* enc        = (const float*)d_in[0];
  const float* attn_in_w  = (const float*)d_in[1];
  const float* attn_in_b  = (const float*)d_in[2];
  const float* attn_out_w = (const float*)d_in[3];
  const float* attn_out_b = (const float*)d_in[4];
  const float* w_ih0 = (const float*)d_in[5];
  const float* w_hh0 = (const float*)d_in[6];
  const float* b_ih0 = (const float*)d_in[7];
  const float* b_hh0 = (const float*)d_in[8];
  const float* w_ih1 = (const float*)d_in[9];
  const float* w_hh1 = (const float*)d_in[10];
  const float* b_ih1 = (const float*)d_in[11];
  const float* b_hh1 = (const float*)d_in[12];
  const float* w_ih2 = (const float*)d_in[13];
  const float* w_hh2 = (const float*)d_in[14];
  const float* b_ih2 = (const float*)d_in[15];
  const float* b_hh2 = (const float*)d_in[16];
  const float* proj_w = (const float*)d_in[17];
  const float* proj_b = (const float*)d_in[18];

  char* ws = (char*)d_ws;
  __hip_bfloat16* Kp  = (__hip_bfloat16*)(ws + OFF_KP);
  __hip_bfloat16* Vp  = (__hip_bfloat16*)(ws + OFF_VP);
  __hip_bfloat16* pl0 = (__hip_bfloat16*)(ws + OFF_PL0);
  __hip_bfloat16* pl1 = (__hip_bfloat16*)(ws + OFF_PL1);
  __hip_bfloat16* pl2 = (__hip_bfloat16*)(ws + OFF_PL2);
  __hip_bfloat16* pwq = (__hip_bfloat16*)(ws + OFF_PWQ);
  __hip_bfloat16* pp  = (__hip_bfloat16*)(ws + OFF_PP);
  float* bl0 = (float*)(ws + OFF_BL0);
  float* bl1 = (float*)(ws + OFF_BL1);
  float* bl2 = (float*)(ws + OFF_BL2);
  float* b2e = (float*)(ws + OFF_B2E);
  __hip_bfloat16* w2e = (__hip_bfloat16*)(ws + OFF_W2E);
  float* wot = (float*)(ws + OFF_WOT);
  char* act  = ws + OFF_ACT;
  unsigned* flags = (unsigned*)(ws + OFF_FLG);

  hipMemsetAsync(flags, 0, 4096, stream);

  // K,V = enc @ {wk,wv}.T + {bk,bv}   (packed [b][h][s][d] bf16)
  gemm_setup<<<dim3(8, 512), 256, 0, stream>>>(enc, attn_in_w + 512 * 512, attn_in_b + 512, Kp, 0);
  gemm_setup<<<dim3(8, 512), 256, 0, stream>>>(enc, attn_in_w + 1024 * 512, attn_in_b + 1024, Vp, 0);
  // W2eff = W2ih @ Wout  (needs Wout^T rows)
  transpose512<<<dim3(16, 16), 256, 0, stream>>>(attn_out_w, wot);
  gemm_setup<<<dim3(8, 32), 256, 0, stream>>>(w_ih2, wot, nullptr, w2e, 1);
  // b2eff = b_ih2 + b_hh2 + W2ih @ b_out
  b2eff_k<<<8, 256, 0, stream>>>(w_ih2, attn_out_b, b_ih2, b_hh2, b2e);
  // fragment packing
  pack_lstm<<<128, 256, 0, stream>>>(w_ih0, nullptr, w_hh0, b_ih0, b_hh0, nullptr, pl0, bl0, 0);
  pack_lstm<<<128, 256, 0, stream>>>(w_ih1, nullptr, w_hh1, b_ih1, b_hh1, nullptr, pl1, bl1, 0);
  pack_lstm<<<128, 256, 0, stream>>>(nullptr, w2e, w_hh2, nullptr, nullptr, b2e, pl2, bl2, 1);
  pack_wq<<<8, 256, 0, stream>>>(attn_in_w, pwq);
  pack_proj<<<5, 256, 0, stream>>>(proj_w, pp);

  DecParams p;
  p.attn_in_b = attn_in_b;
  p.proj_b = proj_b;
  p.packL0 = (const uint4*)pl0; p.packL1 = (const uint4*)pl1; p.packL2 = (const uint4*)pl2;
  p.biasL0 = bl0; p.biasL1 = bl1; p.biasL2 = bl2;
  p.packWq = (const uint4*)pwq; p.packP = (const uint4*)pp;
  p.Kp = Kp; p.Vp = Vp;
  p.h10b = (__hip_bfloat16*)(act + 0);
  p.h11b = (__hip_bfloat16*)(act + 131072);
  p.h2b  = (__hip_bfloat16*)(act + 262144);
  p.ctxb = (__hip_bfloat16*)(act + 393216);
  p.actbase = (uint4*)act;
  p.flags = flags;
  p.out = (float*)d_out;

  // Plain (non-cooperative) launch: 256 blocks x 256 threads, <=160KB LDS and
  // __launch_bounds__(256,1) guarantee >=1 block/CU => all 256 WGs co-resident
  // on 256 CUs. Spin-waits use s_sleep so even 2-blocks/CU placement cannot
  // starve; watchdog bails out after ~WD_TICKS if anything goes wrong.
  decoder_main<<<dim3(256), dim3(256), 0, stream>>>(p);
}

// Round 3
// 157884.155 us; speedup vs baseline: 1.3197x; 1.3197x over previous
//
#include <hip/hip_runtime.h>
#include <hip/hip_bf16.h>

#define DEV_INLINE __device__ __forceinline__

typedef __attribute__((ext_vector_type(8))) short bf16x8;
typedef __attribute__((ext_vector_type(4))) float f32x4;

// Problem constants
constexpr int Bc = 64, Sc = 512, Dc = 512, Hc = 8, HDc = 64, MELc = 80, Tc = 2560;
constexpr int OUTSTRIDE = Tc * MELc; // 204800

// ---------------- workspace layout (bytes) ----------------
constexpr size_t SZ_KP  = 64ull * 8 * 512 * 64 * 2;     // 33554432 bf16 K[b][h][s][d]
constexpr size_t SZ_PL  = 128ull * 2048 * 16;           // 4194304  packed LSTM cell
constexpr size_t OFF_KP  = 0;
constexpr size_t OFF_VP  = OFF_KP + SZ_KP;
constexpr size_t OFF_PL0 = OFF_VP + SZ_KP;
constexpr size_t OFF_PL1 = OFF_PL0 + SZ_PL;
constexpr size_t OFF_PL2 = OFF_PL1 + SZ_PL;
constexpr size_t OFF_PWQ = OFF_PL2 + SZ_PL;             // 524288
constexpr size_t OFF_PP  = OFF_PWQ + 524288;            // 81920
constexpr size_t OFF_BL0 = OFF_PP + 81920;              // 8192
constexpr size_t OFF_BL1 = OFF_BL0 + 8192;
constexpr size_t OFF_BL2 = OFF_BL1 + 8192;
constexpr size_t OFF_B2E = OFF_BL2 + 8192;              // 8192 (f32 2048)
constexpr size_t OFF_W2E = OFF_B2E + 8192;              // 2097152 (bf16 2048x512)
constexpr size_t OFF_WOT = OFF_W2E + 2097152;           // 1048576 (f32 512x512)
constexpr size_t OFF_ACT = OFF_WOT + 1048576;           // 524288: h10[2],h11[2],h2[2],ctx[2]
constexpr size_t OFF_FLG = OFF_ACT + 524288;            // 4096

// ---------------- helpers ----------------
DEV_INLINE float bf2f(short s) { return __uint_as_float(((unsigned)(unsigned short)s) << 16); }
DEV_INLINE short f2bf(float f) { union { __hip_bfloat16 h; short s; } u; u.h = __float2bfloat16(f); return u.s; }
DEV_INLINE float sig_f(float x) { return 1.0f / (1.0f + __expf(-x)); }
DEV_INLINE float tanh_f(float x) {
  float ax = fabsf(x);
  float e = __expf(fminf(2.0f * ax, 80.0f));
  float r = 1.0f - 2.0f / (e + 1.0f);
  return copysignf(r, x);
}
DEV_INLINE bf16x8 cvt8(const float* p) {
  bf16x8 r;
#pragma unroll
  for (int i = 0; i < 8; ++i) r[i] = f2bf(p[i]);
  return r;
}

// ---- MALL-coherent (agent-scope, RELAXED: no cache wb/inv!) 8B access ----
DEV_INLINE unsigned long long ld_dev_u64(const void* p) {
  return __hip_atomic_load((const unsigned long long*)p, __ATOMIC_RELAXED, __HIP_MEMORY_SCOPE_AGENT);
}
DEV_INLINE void st_dev_u64(void* p, unsigned long long v) {
  __hip_atomic_store((unsigned long long*)p, v, __ATOMIC_RELAXED, __HIP_MEMORY_SCOPE_AGENT);
}
DEV_INLINE bf16x8 ld_frag(const __hip_bfloat16* p) {
  union { bf16x8 v; unsigned long long u[2]; } r;
  r.u[0] = ld_dev_u64(p);
  r.u[1] = ld_dev_u64((const char*)p + 8);
  return r.v;
}

// ---------------- setup kernels (unchanged from R2) ----------------
__global__ __launch_bounds__(256) void gemm_setup(const float* __restrict__ A,
                                                  const float* __restrict__ Bt,
                                                  const float* __restrict__ bias,
                                                  __hip_bfloat16* __restrict__ dst,
                                                  int mode) {
  int tid = threadIdx.x, lane = tid & 63, wv = tid >> 6;
  int m0 = blockIdx.y * 64 + wv * 16;
  int nb = blockIdx.x * 64;
  int mrow = m0 + (lane & 15);
  int kb = (lane >> 4) * 8;
  f32x4 acc0 = {0,0,0,0}, acc1 = {0,0,0,0}, acc2 = {0,0,0,0}, acc3 = {0,0,0,0};
  const float* arow = A + (size_t)mrow * 512 + kb;
  const float* b0r = Bt + (size_t)(nb + 0 * 16 + (lane & 15)) * 512 + kb;
  const float* b1r = Bt + (size_t)(nb + 1 * 16 + (lane & 15)) * 512 + kb;
  const float* b2r = Bt + (size_t)(nb + 2 * 16 + (lane & 15)) * 512 + kb;
  const float* b3r = Bt + (size_t)(nb + 3 * 16 + (lane & 15)) * 512 + kb;
  for (int kk = 0; kk < 16; ++kk) {
    bf16x8 af = cvt8(arow + kk * 32);
    acc0 = __builtin_amdgcn_mfma_f32_16x16x32_bf16(af, cvt8(b0r + kk * 32), acc0, 0, 0, 0);
    acc1 = __builtin_amdgcn_mfma_f32_16x16x32_bf16(af, cvt8(b1r + kk * 32), acc1, 0, 0, 0);
    acc2 = __builtin_amdgcn_mfma_f32_16x16x32_bf16(af, cvt8(b2r + kk * 32), acc2, 0, 0, 0);
    acc3 = __builtin_amdgcn_mfma_f32_16x16x32_bf16(af, cvt8(b3r + kk * 32), acc3, 0, 0, 0);
  }
  int col16 = lane & 15, r0 = (lane >> 4) * 4;
  f32x4 accs[4] = {acc0, acc1, acc2, acc3};
#pragma unroll
  for (int nt = 0; nt < 4; ++nt) {
    int n = nb + nt * 16 + col16;
#pragma unroll
    for (int r = 0; r < 4; ++r) {
      int m = m0 + r0 + r;
      float v = accs[nt][r];
      if (mode == 0) {
        v += bias[n];
        int bb = m >> 9, s = m & 511, h = n >> 6, d = n & 63;
        dst[(((size_t)(bb * 8 + h) * 512 + s) * 64) + d] = __float2bfloat16(v);
      } else {
        dst[(size_t)m * 512 + n] = __float2bfloat16(v);
      }
    }
  }
}

__global__ __launch_bounds__(256) void transpose512(const float* __restrict__ in, float* __restrict__ out) {
  __shared__ float tl[32][33];
  int x = threadIdx.x & 31, ty = threadIdx.x >> 5;
  int bx = blockIdx.x * 32, by = blockIdx.y * 32;
#pragma unroll
  for (int r = 0; r < 4; ++r) tl[ty + r * 8][x] = in[(size_t)(by + ty + r * 8) * 512 + bx + x];
  __syncthreads();
#pragma unroll
  for (int r = 0; r < 4; ++r) out[(size_t)(bx + ty + r * 8) * 512 + by + x] = tl[x][ty + r * 8];
}

__global__ __launch_bounds__(256) void b2eff_k(const float* __restrict__ w2ih, const float* __restrict__ bout,
                                               const float* __restrict__ bih, const float* __restrict__ bhh,
                                               float* __restrict__ dst) {
  int g = blockIdx.x * 256 + threadIdx.x;
  float acc = bih[g] + bhh[g];
  const float* row = w2ih + (size_t)g * 512;
  for (int k = 0; k < 512; ++k) acc += row[k] * bout[k];
  dst[g] = acc;
}

__global__ __launch_bounds__(256) void pack_lstm(const float* __restrict__ lo_f32,
                                                 const __hip_bfloat16* __restrict__ lo_bf16,
                                                 const float* __restrict__ hi_f32,
                                                 const float* __restrict__ b1, const float* __restrict__ b2,
                                                 const float* __restrict__ b_pre,
                                                 __hip_bfloat16* __restrict__ dst, float* __restrict__ bias_out,
                                                 int mode) {
  int u = blockIdx.x, tid = threadIdx.x;
  for (int rep = 0; rep < 8; ++rep) {
    int slot = rep * 256 + tid;            // 0..2047
    int kk = slot >> 6, lane = slot & 63;
    int n16 = lane & 15, gate = n16 >> 2, jj = n16 & 3;
    int srow = gate * 512 + u * 4 + jj;
    int k = kk * 32 + (lane >> 4) * 8;
    __hip_bfloat16 tmp[8];
    if (k < 512) {
      if (mode == 0) {
#pragma unroll
        for (int i = 0; i < 8; ++i) tmp[i] = __float2bfloat16(lo_f32[(size_t)srow * 512 + k + i]);
      } else {
#pragma unroll
        for (int i = 0; i < 8; ++i) tmp[i] = lo_bf16[(size_t)srow * 512 + k + i];
      }
    } else {
#pragma unroll
      for (int i = 0; i < 8; ++i) tmp[i] = __float2bfloat16(hi_f32[(size_t)srow * 512 + (k - 512) + i]);
    }
    *(uint4*)(dst + ((size_t)u * 2048 + slot) * 8) = *(uint4*)tmp;
  }
  if (tid < 16) {
    int gate = tid >> 2, jj = tid & 3;
    int srow = gate * 512 + u * 4 + jj;
    bias_out[u * 16 + tid] = (mode == 0) ? (b1[srow] + b2[srow]) : b_pre[srow];
  }
}

__global__ __launch_bounds__(256) void pack_wq(const float* __restrict__ wq, __hip_bfloat16* __restrict__ dst) {
  int h = blockIdx.x, tid = threadIdx.x;
  for (int rep = 0; rep < 16; ++rep) {
    int slot = rep * 256 + tid;            // 0..4095: nt*1024 + kk*64 + lane
    int nt = slot >> 10, kk = (slot >> 6) & 15, lane = slot & 63;
    int srow = h * 64 + nt * 16 + (lane & 15);
    int k = kk * 32 + (lane >> 4) * 8;
    __hip_bfloat16 tmp[8];
#pragma unroll
    for (int i = 0; i < 8; ++i) tmp[i] = __float2bfloat16(wq[(size_t)srow * 512 + k + i]);
    *(uint4*)(dst + ((size_t)h * 4096 + slot) * 8) = *(uint4*)tmp;
  }
}

__global__ __launch_bounds__(256) void pack_proj(const float* __restrict__ pw, __hip_bfloat16* __restrict__ dst) {
  int u5 = blockIdx.x, tid = threadIdx.x;
  for (int rep = 0; rep < 4; ++rep) {
    int slot = rep * 256 + tid;            // 0..1023: kk*64 + lane
    int kk = slot >> 6, lane = slot & 63;
    int srow = u5 * 16 + (lane & 15);
    int k = kk * 32 + (lane >> 4) * 8;
    __hip_bfloat16 tmp[8];
#pragma unroll
    for (int i = 0; i < 8; ++i) tmp[i] = __float2bfloat16(pw[(size_t)srow * 512 + k + i]);
    *(uint4*)(dst + ((size_t)u5 * 1024 + slot) * 8) = *(uint4*)tmp;
  }
}

// ---------------- main persistent decoder ----------------
struct DecParams {
  const float* attn_in_b;
  const float* proj_b;
  const uint4* packL0; const uint4* packL1; const uint4* packL2;
  const float* biasL0; const float* biasL1; const float* biasL2;
  const uint4* packWq; const uint4* packP;
  const __hip_bfloat16* Kp; const __hip_bfloat16* Vp;
  __hip_bfloat16* h10b; __hip_bfloat16* h11b; __hip_bfloat16* h2b; __hip_bfloat16* ctxb;
  unsigned long long* actbase;
  unsigned* flags;
  float* out;
};

constexpr unsigned long long WD_TICKS = 200000000ull;   // watchdog: ~2 s of s_memrealtime

// NO release/acquire cache ops anywhere in the hot loop: agent-scope RELEASE
// would emit buffer_wbl2 (flush whole dirty L2) and ACQUIRE buffer_inv
// (invalidate whole L2), evicting the stationary weights every stage — that
// was R2's 81us/step. Ordering instead: s_waitcnt vmcnt(0) (data stores,
// which are sc1 write-through, are ack'd at the coherence point) before the
// relaxed flag store.
DEV_INLINE void publish_flag(unsigned* flags, int wg, unsigned id, int tid) {
  __builtin_amdgcn_s_waitcnt(0);   // drain this wave's vmem (incl. coherent stores)
  __syncthreads();                 // all waves reached here (each drained before barrier)
  if (tid == 0)
    __hip_atomic_store(&flags[wg], id, __ATOMIC_RELAXED, __HIP_MEMORY_SCOPE_AGENT);
}

// returns false on watchdog timeout (block-uniform)
DEV_INLINE bool wait_flags(unsigned* flags, int base, int count, unsigned id, int tid,
                           unsigned long long t0, int* bail) {
  if (tid < 64) {
    for (;;) {
      bool ok = true;
      for (int i = tid; i < count; i += 64)
        ok &= (__hip_atomic_load(&flags[base + i], __ATOMIC_RELAXED, __HIP_MEMORY_SCOPE_AGENT) >= id);
      if (__all(ok ? 1 : 0)) break;
      if (__builtin_amdgcn_s_memrealtime() - t0 > WD_TICKS) { if (tid == 0) *bail = 1; break; }
      __builtin_amdgcn_s_sleep(2);
    }
  }
  __syncthreads();
  if (*bail) return false;
  return true;   // no acquire: producer's data went through coherent (sc1) stores
}

// One LSTM slice: gates[64,16] = [actLo|actHi][64,1024] @ Wslice.T  → h,c for 4 units
// Activation reads + h writes are MALL-coherent; weights are plain cached loads.
DEV_INLINE void lstm_slice(int tid, const uint4* packW, const float* bias,
                           const __hip_bfloat16* actLo, const __hip_bfloat16* actHi,
                           float* c_lds, __hip_bfloat16* hout_unit, float* gates,
                           unsigned short* hred) {
  int lane = tid & 63, wv = tid >> 6;
  int m = wv * 16 + (lane & 15);
  int kb = (lane >> 4) * 8;
  f32x4 acc = {0,0,0,0};
  const __hip_bfloat16* pLo = actLo + (size_t)m * 512 + kb;
  const __hip_bfloat16* pHi = actHi + (size_t)m * 512 + kb;
#pragma unroll 8
  for (int kk = 0; kk < 16; ++kk) {
    bf16x8 a = ld_frag(pLo + kk * 32);
    bf16x8 b = *(const bf16x8*)(packW + kk * 64 + lane);
    acc = __builtin_amdgcn_mfma_f32_16x16x32_bf16(a, b, acc, 0, 0, 0);
  }
#pragma unroll 8
  for (int kk = 0; kk < 16; ++kk) {
    bf16x8 a = ld_frag(pHi + kk * 32);
    bf16x8 b = *(const bf16x8*)(packW + (16 + kk) * 64 + lane);
    acc = __builtin_amdgcn_mfma_f32_16x16x32_bf16(a, b, acc, 0, 0, 0);
  }
  int row0 = wv * 16 + ((lane >> 4) << 2), col = lane & 15;
#pragma unroll
  for (int r = 0; r < 4; ++r) gates[(row0 + r) * 17 + col] = acc[r];
  __syncthreads();
  int bb = tid >> 2, j = tid & 3;
  float gi = gates[bb * 17 + j]      + bias[j];
  float gf = gates[bb * 17 + 4 + j]  + bias[4 + j];
  float gg = gates[bb * 17 + 8 + j]  + bias[8 + j];
  float go = gates[bb * 17 + 12 + j] + bias[12 + j];
  float c = c_lds[tid];
  c = sig_f(gf) * c + sig_f(gi) * tanh_f(gg);
  float h = sig_f(go) * tanh_f(c);
  c_lds[tid] = c;
  hred[tid] = (unsigned short)f2bf(h);     // hred[b*4 + j]
  __syncthreads();
  if (tid < 64)
    st_dev_u64(hout_unit + (size_t)tid * 512, *(const unsigned long long*)(hred + tid * 4));
}

DEV_INLINE void proj_slice(int tid, const uint4* packW, const float* bias,
                           const __hip_bfloat16* actLo, float* outp, int u5) {
  int lane = tid & 63, wv = tid >> 6;
  int m = wv * 16 + (lane & 15);
  int kb = (lane >> 4) * 8;
  f32x4 acc = {0,0,0,0};
  const __hip_bfloat16* pA = actLo + (size_t)m * 512 + kb;
#pragma unroll 8
  for (int kk = 0; kk < 16; ++kk) {
    bf16x8 a = ld_frag(pA + kk * 32);
    bf16x8 b = *(const bf16x8*)(packW + kk * 64 + lane);
    acc = __builtin_amdgcn_mfma_f32_16x16x32_bf16(a, b, acc, 0, 0, 0);
  }
  int col = lane & 15, row0 = wv * 16 + ((lane >> 4) << 2);
  float bia = bias[u5 * 16 + col];
#pragma unroll
  for (int r = 0; r < 4; ++r)
    outp[(size_t)(row0 + r) * OUTSTRIDE + u5 * 16 + col] = acc[r] + bia;
}

__global__ __launch_bounds__(256, 1) void decoder_main(DecParams P) {
  const int wg = blockIdx.x, tid = threadIdx.x;
  const int lane = tid & 63, wv = tid >> 6;
  __shared__ float gates[64 * 17];
  __shared__ float qls[16 * 68];
  __shared__ float sco[2 * 512];
  __shared__ float red[2 * 16 * 64];
  __shared__ float cA[256], cB[256];
  __shared__ float smx[4], ssum[4], sinv[2];
  __shared__ unsigned long long hred64[64];
  __shared__ unsigned long long cred64[32];
  __shared__ int s_bail;
  unsigned short* hred = (unsigned short*)hred64;
  unsigned short* credu = (unsigned short*)cred64;

  const unsigned long long t0 = __builtin_amdgcn_s_memrealtime();
  const int hh = wg >> 5;
  const int b0 = (wg & 31) * 2;
  const int bblk = b0 & ~15;
  const uint4* myL0 = P.packL0 + (size_t)wg * 2048;
  const uint4* myL1 = P.packL1 + (size_t)(wg - 128) * 2048;
  const uint4* myL2 = P.packL2 + (size_t)wg * 2048;
  const uint4* myWq = P.packWq + (size_t)hh * 4096;

  if (tid == 0) s_bail = 0;
  cA[tid] = 0.0f; cB[tid] = 0.0f;

  // zero activation buffers COHERENTLY (MALL holds 0xAA poison; agent-scope
  // loads bypass L2, so plain stores would not be observed)
  st_dev_u64(P.actbase + (size_t)wg * 256 + tid, 0ull);
  publish_flag(P.flags, wg, 1u, tid);
  // pre-loop global barrier: everyone's zeroing visible before first reads
  if (!wait_flags(P.flags, 0, 256, 1u, tid, t0, &s_bail)) goto bail;

  for (int t = 0; t < Tc; ++t) {
    const int cur = t & 1, pv = cur ^ 1;
    const unsigned idA = 4u * t + 1, idApub = 4u * t + 2, idBpub = 4u * t + 3,
                   idCpub = 4u * t + 4, idDpub = 4u * t + 5;
    __hip_bfloat16* h10c = P.h10b + cur * 32768; __hip_bfloat16* h10p = P.h10b + pv * 32768;
    __hip_bfloat16* h11c = P.h11b + cur * 32768; __hip_bfloat16* h11p = P.h11b + pv * 32768;
    __hip_bfloat16* h2c  = P.h2b  + cur * 32768; __hip_bfloat16* h2p  = P.h2b  + pv * 32768;
    __hip_bfloat16* ctxc = P.ctxb + cur * 32768;

    if (wg < 128) {
      // ---- stage A: LSTM0 ----
      if (!wait_flags(P.flags, 0, 128, idA, tid, t0, &s_bail)) goto bail;
      lstm_slice(tid, myL0, P.biasL0 + wg * 16, h2p, h10p, cA, h10c + wg * 4, gates, hred);
      publish_flag(P.flags, wg, idApub, tid);
    } else {
      if (wg < 133 && t > 0) {
        if (!wait_flags(P.flags, 0, 128, idA, tid, t0, &s_bail)) goto bail;
        proj_slice(tid, P.packP + (size_t)(wg - 128) * 1024, P.proj_b, h2p,
                   P.out + (size_t)(t - 1) * MELc, wg - 128);
      }
      // ---- stage B: LSTM1 ----
      if (!wait_flags(P.flags, 0, 128, idApub, tid, t0, &s_bail)) goto bail;
      lstm_slice(tid, myL1, P.biasL1 + (wg - 128) * 16, h10c, h11p, cA,
                 h11c + (wg - 128) * 4, gates, hred);
      publish_flag(P.flags, wg, idBpub, tid);
    }

    // ---- stage C: attention (all WGs, 2 (b,h) pairs each) ----
    if (!wait_flags(P.flags, 128, 128, idBpub, tid, t0, &s_bail)) goto bail;
    {
      // q = (h11 @ Wq[h].T + bq) * 0.125  via MFMA over 16 batch rows
      int m = bblk + (lane & 15);
      int kb2 = (lane >> 4) * 8;
      f32x4 acc = {0,0,0,0};
      const __hip_bfloat16* pA = h11c + (size_t)m * 512 + kb2;
      const uint4* pB = myWq + wv * 1024;
#pragma unroll 8
      for (int kk = 0; kk < 16; ++kk) {
        bf16x8 a = ld_frag(pA + kk * 32);
        bf16x8 b = *(const bf16x8*)(pB + kk * 64 + lane);
        acc = __builtin_amdgcn_mfma_f32_16x16x32_bf16(a, b, acc, 0, 0, 0);
      }
      int col = lane & 15, row0 = (lane >> 4) << 2;
      int dg = wv * 16 + col;
      float bq = P.attn_in_b[hh * 64 + dg];
#pragma unroll
      for (int r = 0; r < 4; ++r) qls[(row0 + r) * 68 + dg] = (acc[r] + bq) * 0.125f;
    }
    __syncthreads();
    {
      // scores: 2 pairs x 512 positions, 4 per thread (K,V are plain cached loads)
      int p = tid >> 7, si = tid & 127;
      int bb = b0 + p;
      int qrow = (b0 & 15) + p;
      const float* qv = qls + qrow * 68;
      const __hip_bfloat16* Kb = P.Kp + ((size_t)(bb * 8 + hh) * 512) * 64;
#pragma unroll
      for (int ss = 0; ss < 4; ++ss) {
        int s = si * 4 + ss;
        const bf16x8* kr = (const bf16x8*)(Kb + (size_t)s * 64);
        float acc = 0.0f;
#pragma unroll
        for (int i = 0; i < 8; ++i) {
          bf16x8 kvv = kr[i];
#pragma unroll
          for (int jj = 0; jj < 8; ++jj) acc += qv[i * 8 + jj] * bf2f(kvv[jj]);
        }
        sco[p * 512 + s] = acc;
      }
    }
    __syncthreads();
    {
      // softmax (unnormalized exp in LDS + 1/sum)
      int p = wv >> 1, half = wv & 1;
      int idx = tid & 127;
      float mx = -1e30f;
#pragma unroll
      for (int ss = 0; ss < 4; ++ss) mx = fmaxf(mx, sco[p * 512 + idx * 4 + ss]);
#pragma unroll
      for (int off = 32; off; off >>= 1) mx = fmaxf(mx, __shfl_xor(mx, off));
      if (lane == 0) smx[p * 2 + half] = mx;
      __syncthreads();
      float m = fmaxf(smx[p * 2], smx[p * 2 + 1]);
      float sum = 0.0f;
#pragma unroll
      for (int ss = 0; ss < 4; ++ss) {
        int ix = p * 512 + idx * 4 + ss;
        float e = __expf(sco[ix] - m);
        sco[ix] = e; sum += e;
      }
#pragma unroll
      for (int off = 32; off; off >>= 1) sum += __shfl_xor(sum, off);
      if (lane == 0) ssum[p * 2 + half] = sum;
      __syncthreads();
      if (tid < 2) sinv[tid] = 1.0f / (ssum[tid * 2] + ssum[tid * 2 + 1]);
    }
    __syncthreads();
    {
      // ctx = p . V   (per pair: 2 waves split s-range; lane = (sg, dj))
      int p = wv >> 1, half = wv & 1;
      int bb = b0 + p;
      int sg = lane >> 3, dj = lane & 7;
      const __hip_bfloat16* Vb = P.Vp + ((size_t)(bb * 8 + hh) * 512) * 64;
      float a8[8] = {0,0,0,0,0,0,0,0};
      for (int it = 0; it < 32; ++it) {
        int s = half * 256 + it * 8 + sg;
        float w = sco[p * 512 + s];
        bf16x8 v = *(const bf16x8*)(Vb + (size_t)s * 64 + dj * 8);
#pragma unroll
        for (int e = 0; e < 8; ++e) a8[e] += w * bf2f(v[e]);
      }
      float* rp = red + ((p * 16 + half * 8 + sg) * 64) + dj * 8;
#pragma unroll
      for (int e = 0; e < 8; ++e) rp[e] = a8[e];
    }
    __syncthreads();
    if (tid < 128) {
      int p = tid >> 6, d = tid & 63;
      float sacc = 0.0f;
#pragma unroll
      for (int k = 0; k < 16; ++k) sacc += red[(p * 16 + k) * 64 + d];
      sacc *= sinv[p];
      credu[p * 64 + d] = (unsigned short)f2bf(sacc);
    }
    __syncthreads();
    if (tid < 32) {
      int p = tid >> 4, q = tid & 15;
      st_dev_u64(ctxc + (size_t)(b0 + p) * 512 + hh * 64 + q * 4, cred64[p * 16 + q]);
    }
    publish_flag(P.flags, wg, idCpub, tid);

    if (wg < 128) {
      // ---- stage D: LSTM2 (out-proj folded into W2eff) ----
      if (!wait_flags(P.flags, 0, 256, idCpub, tid, t0, &s_bail)) goto bail;
      lstm_slice(tid, myL2, P.biasL2 + wg * 16, ctxc, h2p, cB, h2c + wg * 4, gates, hred);
      publish_flag(P.flags, wg, idDpub, tid);
    }
  }

  // final projection for t = T-1
  if (wg >= 128 && wg < 133) {
    if (wait_flags(P.flags, 0, 128, 4u * (Tc - 1) + 5, tid, t0, &s_bail))
      proj_slice(tid, P.packP + (size_t)(wg - 128) * 1024, P.proj_b,
                 P.h2b + ((Tc - 1) & 1) * 32768, P.out + (size_t)(Tc - 1) * MELc, wg - 128);
  }
  return;

bail:
  // watchdog fired: unblock peers and exit (wrong output, but no hang)
  publish_flag(P.flags, wg, 0x7F000000u, tid);
}

// ---------------- launcher ----------------
extern "C" void kernel_launch(void* const* d_in, const int* in_sizes, int n_in,
                              void* d_out, int out_size, void* d_ws, size_t ws_size,
                              hipStream_t stream) {
  const float* enc        = (const float*)d_in[0];
  const float* attn_in_w  = (const float*)d_in[1];
  const float* attn_in_b  = (const float*)d_in[2];
  const float* attn_out_w = (const float*)d_in[3];
  const float* attn_out_b = (const float*)d_in[4];
  const float* w_ih0 = (const float*)d_in[5];
  const float* w_hh0 = (const float*)d_in[6];
  const float* b_ih0 = (const float*)d_in[7];
  const float* b_hh0 = (const float*)d_in[8];
  const float* w_ih1 = (const float*)d_in[9];
  const float* w_hh1 = (const float*)d_in[10];
  const float* b_ih1 = (const float*)d_in[11];
  const float* b_hh1 = (const float*)d_in[12];
  const float* w_ih2 = (const float*)d_in[13];
  const float* w_hh2 = (const float*)d_in[14];
  const float* b_ih2 = (const float*)d_in[15];
  const float* b_hh2 = (const float*)d_in[16];
  const float* proj_w = (const float*)d_in[17];
  const float* proj_b = (const float*)d_in[18];

  char* ws = (char*)d_ws;
  __hip_bfloat16* Kp  = (__hip_bfloat16*)(ws + OFF_KP);
  __hip_bfloat16* Vp  = (__hip_bfloat16*)(ws + OFF_VP);
  __hip_bfloat16* pl0 = (__hip_bfloat16*)(ws + OFF_PL0);
  __hip_bfloat16* pl1 = (__hip_bfloat16*)(ws + OFF_PL1);
  __hip_bfloat16* pl2 = (__hip_bfloat16*)(ws + OFF_PL2);
  __hip_bfloat16* pwq = (__hip_bfloat16*)(ws + OFF_PWQ);
  __hip_bfloat16* pp  = (__hip_bfloat16*)(ws + OFF_PP);
  float* bl0 = (float*)(ws + OFF_BL0);
  float* bl1 = (float*)(ws + OFF_BL1);
  float* bl2 = (float*)(ws + OFF_BL2);
  float* b2e = (float*)(ws + OFF_B2E);
  __hip_bfloat16* w2e = (__hip_bfloat16*)(ws + OFF_W2E);
  float* wot = (float*)(ws + OFF_WOT);
  char* act  = ws + OFF_ACT;
  unsigned* flags = (unsigned*)(ws + OFF_FLG);

  hipMemsetAsync(flags, 0, 4096, stream);

  // K,V = enc @ {wk,wv}.T + {bk,bv}   (packed [b][h][s][d] bf16)
  gemm_setup<<<dim3(8, 512), 256, 0, stream>>>(enc, attn_in_w + 512 * 512, attn_in_b + 512, Kp, 0);
  gemm_setup<<<dim3(8, 512), 256, 0, stream>>>(enc, attn_in_w + 1024 * 512, attn_in_b + 1024, Vp, 0);
  // W2eff = W2ih @ Wout  (needs Wout^T rows)
  transpose512<<<dim3(16, 16), 256, 0, stream>>>(attn_out_w, wot);
  gemm_setup<<<dim3(8, 32), 256, 0, stream>>>(w_ih2, wot, nullptr, w2e, 1);
  // b2eff = b_ih2 + b_hh2 + W2ih @ b_out
  b2eff_k<<<8, 256, 0, stream>>>(w_ih2, attn_out_b, b_ih2, b_hh2, b2e);
  // fragment packing
  pack_lstm<<<128, 256, 0, stream>>>(w_ih0, nullptr, w_hh0, b_ih0, b_hh0, nullptr, pl0, bl0, 0);
  pack_lstm<<<128, 256, 0, stream>>>(w_ih1, nullptr, w_hh1, b_ih1, b_hh1, nullptr, pl1, bl1, 0);
  pack_lstm<<<128, 256, 0, stream>>>(nullptr, w2e, w_hh2, nullptr, nullptr, b2e, pl2, bl2, 1);
  pack_wq<<<8, 256, 0, stream>>>(attn_in_w, pwq);
  pack_proj<<<5, 256, 0, stream>>>(proj_w, pp);

  DecParams p;
  p.attn_in_b = attn_in_b;
  p.proj_b = proj_b;
  p.packL0 = (const uint4*)pl0; p.packL1 = (const uint4*)pl1; p.packL2 = (const uint4*)pl2;
  p.biasL0 = bl0; p.biasL1 = bl1; p.biasL2 = bl2;
  p.packWq = (const uint4*)pwq; p.packP = (const uint4*)pp;
  p.Kp = Kp; p.Vp = Vp;
  p.h10b = (__hip_bfloat16*)(act + 0);
  p.h11b = (__hip_bfloat16*)(act + 131072);
  p.h2b  = (__hip_bfloat16*)(act + 262144);
  p.ctxb = (__hip_bfloat16*)(act + 393216);
  p.actbase = (unsigned long long*)act;
  p.flags = flags;
  p.out = (float*)d_out;

  // Plain (non-cooperative) launch: 256 blocks x 256 threads, <=160KB LDS and
  // __launch_bounds__(256,1) guarantee >=1 block/CU => all 256 WGs co-resident
  // on 256 CUs. Spin-waits use s_sleep; watchdog bails after ~WD_TICKS.
  decoder_main<<<dim3(256), dim3(256), 0, stream>>>(p);
}

// Round 4
// 110877.625 us; speedup vs baseline: 1.8792x; 1.4239x over previous
//
#include <hip/hip_runtime.h>
#include <hip/hip_bf16.h>
#include <hip/hip_fp8.h>

#define DEV_INLINE __device__ __forceinline__

typedef __attribute__((ext_vector_type(8))) short bf16x8;
typedef __attribute__((ext_vector_type(4))) float f32x4;
typedef unsigned long long ull;

// Problem constants
constexpr int Bc = 64, Sc = 512, Dc = 512, Hc = 8, HDc = 64, MELc = 80, Tc = 2560;
constexpr int OUTSTRIDE = Tc * MELc; // 204800

// ---------------- workspace layout (bytes) ----------------
constexpr size_t SZ_KP8 = 64ull * 8 * 512 * 64;         // 16777216 fp8 K[b][h][s][d]
constexpr size_t SZ_VP  = 64ull * 8 * 512 * 64 * 2;     // 33554432 bf16 V[b][h][s][d]
constexpr size_t SZ_PL  = 128ull * 2048 * 16;           // 4194304  packed LSTM cell
constexpr size_t OFF_KP8 = 0;
constexpr size_t OFF_VP  = OFF_KP8 + SZ_KP8;
constexpr size_t OFF_PL0 = OFF_VP + SZ_VP;
constexpr size_t OFF_PL1 = OFF_PL0 + SZ_PL;
constexpr size_t OFF_PL2 = OFF_PL1 + SZ_PL;
constexpr size_t OFF_PWQ = OFF_PL2 + SZ_PL;             // 524288
constexpr size_t OFF_PP  = OFF_PWQ + 524288;            // 81920
constexpr size_t OFF_BL0 = OFF_PP + 81920;              // 8192
constexpr size_t OFF_BL1 = OFF_BL0 + 8192;
constexpr size_t OFF_BL2 = OFF_BL1 + 8192;
constexpr size_t OFF_B2E = OFF_BL2 + 8192;              // 8192 (f32 2048)
constexpr size_t OFF_W2E = OFF_B2E + 8192;              // 2097152 (bf16 2048x512)
constexpr size_t OFF_WOT = OFF_W2E + 2097152;           // 1048576 (f32 512x512)
constexpr size_t OFF_ACT = OFF_WOT + 1048576;           // 524288: h10[2],h11[2],h2[2],ctx[2]
constexpr size_t OFF_FLG = OFF_ACT + 524288;            // 4096

constexpr unsigned DYN_LDS = 137344;                    // dynamic LDS carve (see kernel)

// ---------------- helpers ----------------
DEV_INLINE float bf2f(short s) { return __uint_as_float(((unsigned)(unsigned short)s) << 16); }
DEV_INLINE short f2bf(float f) { union { __hip_bfloat16 h; short s; } u; u.h = __float2bfloat16(f); return u.s; }
DEV_INLINE float sig_f(float x) { return 1.0f / (1.0f + __expf(-x)); }
DEV_INLINE float tanh_f(float x) {
  float ax = fabsf(x);
  float e = __expf(fminf(2.0f * ax, 80.0f));
  float r = 1.0f - 2.0f / (e + 1.0f);
  return copysignf(r, x);
}
DEV_INLINE bf16x8 cvt8(const float* p) {
  bf16x8 r;
#pragma unroll
  for (int i = 0; i < 8; ++i) r[i] = f2bf(p[i]);
  return r;
}
DEV_INLINE float fp8tof(unsigned v) {
  __hip_fp8_e4m3 t; t.__x = (__hip_fp8_storage_t)v; return (float)t;
}

// ---- MALL-coherent (agent-scope RELAXED: no cache wb/inv) 8B access ----
DEV_INLINE ull ld_dev_u64(const void* p) {
  return __hip_atomic_load((const ull*)p, __ATOMIC_RELAXED, __HIP_MEMORY_SCOPE_AGENT);
}
DEV_INLINE void st_dev_u64(void* p, ull v) {
  __hip_atomic_store((ull*)p, v, __ATOMIC_RELAXED, __HIP_MEMORY_SCOPE_AGENT);
}
DEV_INLINE bf16x8 ld_frag(const __hip_bfloat16* p) {
  union { bf16x8 v; ull u[2]; } r;
  r.u[0] = ld_dev_u64(p);
  r.u[1] = ld_dev_u64((const char*)p + 8);
  return r.v;
}

// ---------------- setup kernels ----------------
// out = A[M,512] @ Bt[rows][512].T (bf16 MFMA from fp32)
// mode 0: KV bf16 pack [b][h][s][d] + bias; mode 1: row-major bf16 [M,512];
// mode 2: KV fp8-e4m3 pack [b][h][s][d] + bias
__global__ __launch_bounds__(256) void gemm_setup(const float* __restrict__ A,
                                                  const float* __restrict__ Bt,
                                                  const float* __restrict__ bias,
                                                  __hip_bfloat16* __restrict__ dst,
                                                  unsigned char* __restrict__ dst8,
                                                  int mode) {
  int tid = threadIdx.x, lane = tid & 63, wv = tid >> 6;
  int m0 = blockIdx.y * 64 + wv * 16;
  int nb = blockIdx.x * 64;
  int mrow = m0 + (lane & 15);
  int kb = (lane >> 4) * 8;
  f32x4 acc0 = {0,0,0,0}, acc1 = {0,0,0,0}, acc2 = {0,0,0,0}, acc3 = {0,0,0,0};
  const float* arow = A + (size_t)mrow * 512 + kb;
  const float* b0r = Bt + (size_t)(nb + 0 * 16 + (lane & 15)) * 512 + kb;
  const float* b1r = Bt + (size_t)(nb + 1 * 16 + (lane & 15)) * 512 + kb;
  const float* b2r = Bt + (size_t)(nb + 2 * 16 + (lane & 15)) * 512 + kb;
  const float* b3r = Bt + (size_t)(nb + 3 * 16 + (lane & 15)) * 512 + kb;
  for (int kk = 0; kk < 16; ++kk) {
    bf16x8 af = cvt8(arow + kk * 32);
    acc0 = __builtin_amdgcn_mfma_f32_16x16x32_bf16(af, cvt8(b0r + kk * 32), acc0, 0, 0, 0);
    acc1 = __builtin_amdgcn_mfma_f32_16x16x32_bf16(af, cvt8(b1r + kk * 32), acc1, 0, 0, 0);
    acc2 = __builtin_amdgcn_mfma_f32_16x16x32_bf16(af, cvt8(b2r + kk * 32), acc2, 0, 0, 0);
    acc3 = __builtin_amdgcn_mfma_f32_16x16x32_bf16(af, cvt8(b3r + kk * 32), acc3, 0, 0, 0);
  }
  int col16 = lane & 15, r0 = (lane >> 4) * 4;
  f32x4 accs[4] = {acc0, acc1, acc2, acc3};
#pragma unroll
  for (int nt = 0; nt < 4; ++nt) {
    int n = nb + nt * 16 + col16;
#pragma unroll
    for (int r = 0; r < 4; ++r) {
      int m = m0 + r0 + r;
      float v = accs[nt][r];
      if (mode == 0) {
        v += bias[n];
        int bb = m >> 9, s = m & 511, h = n >> 6, d = n & 63;
        dst[(((size_t)(bb * 8 + h) * 512 + s) * 64) + d] = __float2bfloat16(v);
      } else if (mode == 2) {
        v += bias[n];
        int bb = m >> 9, s = m & 511, h = n >> 6, d = n & 63;
        __hip_fp8_e4m3 q(v);
        dst8[(((size_t)(bb * 8 + h) * 512 + s) * 64) + d] = (unsigned char)q.__x;
      } else {
        dst[(size_t)m * 512 + n] = __float2bfloat16(v);
      }
    }
  }
}

__global__ __launch_bounds__(256) void transpose512(const float* __restrict__ in, float* __restrict__ out) {
  __shared__ float tl[32][33];
  int x = threadIdx.x & 31, ty = threadIdx.x >> 5;
  int bx = blockIdx.x * 32, by = blockIdx.y * 32;
#pragma unroll
  for (int r = 0; r < 4; ++r) tl[ty + r * 8][x] = in[(size_t)(by + ty + r * 8) * 512 + bx + x];
  __syncthreads();
#pragma unroll
  for (int r = 0; r < 4; ++r) out[(size_t)(bx + ty + r * 8) * 512 + by + x] = tl[x][ty + r * 8];
}

__global__ __launch_bounds__(256) void b2eff_k(const float* __restrict__ w2ih, const float* __restrict__ bout,
                                               const float* __restrict__ bih, const float* __restrict__ bhh,
                                               float* __restrict__ dst) {
  int g = blockIdx.x * 256 + threadIdx.x;
  float acc = bih[g] + bhh[g];
  const float* row = w2ih + (size_t)g * 512;
  for (int k = 0; k < 512; ++k) acc += row[k] * bout[k];
  dst[g] = acc;
}

// Pack one LSTM cell slice (4 units): col16 = gate*4+unit, K-cat [lo|hi], slot = kk*64+lane
__global__ __launch_bounds__(256) void pack_lstm(const float* __restrict__ lo_f32,
                                                 const __hip_bfloat16* __restrict__ lo_bf16,
                                                 const float* __restrict__ hi_f32,
                                                 const float* __restrict__ b1, const float* __restrict__ b2,
                                                 const float* __restrict__ b_pre,
                                                 __hip_bfloat16* __restrict__ dst, float* __restrict__ bias_out,
                                                 int mode) {
  int u = blockIdx.x, tid = threadIdx.x;
  for (int rep = 0; rep < 8; ++rep) {
    int slot = rep * 256 + tid;            // 0..2047
    int kk = slot >> 6, lane = slot & 63;
    int n16 = lane & 15, gate = n16 >> 2, jj = n16 & 3;
    int srow = gate * 512 + u * 4 + jj;
    int k = kk * 32 + (lane >> 4) * 8;
    __hip_bfloat16 tmp[8];
    if (k < 512) {
      if (mode == 0) {
#pragma unroll
        for (int i = 0; i < 8; ++i) tmp[i] = __float2bfloat16(lo_f32[(size_t)srow * 512 + k + i]);
      } else {
#pragma unroll
        for (int i = 0; i < 8; ++i) tmp[i] = lo_bf16[(size_t)srow * 512 + k + i];
      }
    } else {
#pragma unroll
      for (int i = 0; i < 8; ++i) tmp[i] = __float2bfloat16(hi_f32[(size_t)srow * 512 + (k - 512) + i]);
    }
    *(uint4*)(dst + ((size_t)u * 2048 + slot) * 8) = *(uint4*)tmp;
  }
  if (tid < 16) {
    int gate = tid >> 2, jj = tid & 3;
    int srow = gate * 512 + u * 4 + jj;
    bias_out[u * 16 + tid] = (mode == 0) ? (b1[srow] + b2[srow]) : b_pre[srow];
  }
}

__global__ __launch_bounds__(256) void pack_wq(const float* __restrict__ wq, __hip_bfloat16* __restrict__ dst) {
  int h = blockIdx.x, tid = threadIdx.x;
  for (int rep = 0; rep < 16; ++rep) {
    int slot = rep * 256 + tid;            // nt*1024 + kk*64 + lane
    int nt = slot >> 10, kk = (slot >> 6) & 15, lane = slot & 63;
    int srow = h * 64 + nt * 16 + (lane & 15);
    int k = kk * 32 + (lane >> 4) * 8;
    __hip_bfloat16 tmp[8];
#pragma unroll
    for (int i = 0; i < 8; ++i) tmp[i] = __float2bfloat16(wq[(size_t)srow * 512 + k + i]);
    *(uint4*)(dst + ((size_t)h * 4096 + slot) * 8) = *(uint4*)tmp;
  }
}

__global__ __launch_bounds__(256) void pack_proj(const float* __restrict__ pw, __hip_bfloat16* __restrict__ dst) {
  int u5 = blockIdx.x, tid = threadIdx.x;
  for (int rep = 0; rep < 4; ++rep) {
    int slot = rep * 256 + tid;            // kk*64 + lane
    int kk = slot >> 6, lane = slot & 63;
    int srow = u5 * 16 + (lane & 15);
    int k = kk * 32 + (lane >> 4) * 8;
    __hip_bfloat16 tmp[8];
#pragma unroll
    for (int i = 0; i < 8; ++i) tmp[i] = __float2bfloat16(pw[(size_t)srow * 512 + k + i]);
    *(uint4*)(dst + ((size_t)u5 * 1024 + slot) * 8) = *(uint4*)tmp;
  }
}

// ---------------- main persistent decoder ----------------
struct DecParams {
  const float* attn_in_b;
  const float* proj_b;
  const uint4* packL0; const uint4* packL1; const uint4* packL2;
  const float* biasL0; const float* biasL1; const float* biasL2;
  const uint4* packWq; const uint4* packP;
  const unsigned char* Kp8; const __hip_bfloat16* Vp;
  __hip_bfloat16* h10b; __hip_bfloat16* h11b; __hip_bfloat16* h2b; __hip_bfloat16* ctxb;
  ull* actbase;
  unsigned* flags;
  float* out;
};

constexpr ull WD_TICKS = 200000000ull;   // watchdog

DEV_INLINE void publish_flag(unsigned* flags, int wg, unsigned id, int tid) {
  __builtin_amdgcn_s_waitcnt(0);   // drain this wave's vmem (incl. coherent stores)
  __syncthreads();
  if (tid == 0)
    __hip_atomic_store(&flags[wg], id, __ATOMIC_RELAXED, __HIP_MEMORY_SCOPE_AGENT);
}

DEV_INLINE bool wait_flags(unsigned* flags, int base, int count, unsigned id, int tid,
                           ull t0, int* bail) {
  if (tid < 64) {
    for (;;) {
      bool ok = true;
      for (int i = tid; i < count; i += 64)
        ok &= (__hip_atomic_load(&flags[base + i], __ATOMIC_RELAXED, __HIP_MEMORY_SCOPE_AGENT) >= id);
      if (__all(ok ? 1 : 0)) break;
      if (__builtin_amdgcn_s_memrealtime() - t0 > WD_TICKS) { if (tid == 0) *bail = 1; break; }
      __builtin_amdgcn_s_sleep(1);
    }
  }
  __syncthreads();
  if (*bail) return false;
  return true;
}

// prefetch 16 A-fragments of the STALE half (waves 2,3 only)
DEV_INLINE void prefetch_hi(bf16x8* pf, const __hip_bfloat16* hi, int g, int lane, int wv) {
  if (wv >= 2) {
    const __hip_bfloat16* p = hi + (size_t)(g * 32 + (wv & 1) * 16 + (lane & 15)) * 512 + (lane >> 4) * 8;
#pragma unroll
    for (int kk = 0; kk < 16; ++kk) pf[kk] = ld_frag(p + kk * 32);
  }
}

// One LSTM stage for 32 batch rows (group), 4 hidden units (this WG).
// waves: wv = mt + 2*kh (mt = M-tile of 16, kh = K-half). Weights from LDS.
DEV_INLINE void lstm_stage(int tid, int g, int wgl,
                           const uint4* wlds, const float* bias,
                           const __hip_bfloat16* lo, const bf16x8* pf,
                           float* cstate, __hip_bfloat16* hc,
                           float* pred, ull* st64) {
  const int lane = tid & 63, wv = tid >> 6, mt = wv & 1, kh = wv >> 1;
  f32x4 acc = {0,0,0,0};
  if (kh == 0) {
    const __hip_bfloat16* pA = lo + (size_t)(g * 32 + mt * 16 + (lane & 15)) * 512 + (lane >> 4) * 8;
#pragma unroll
    for (int kk = 0; kk < 16; ++kk) {
      bf16x8 a = ld_frag(pA + kk * 32);
      bf16x8 b = *(const bf16x8*)(wlds + kk * 64 + lane);
      acc = __builtin_amdgcn_mfma_f32_16x16x32_bf16(a, b, acc, 0, 0, 0);
    }
  } else {
#pragma unroll
    for (int kk = 0; kk < 16; ++kk) {
      bf16x8 b = *(const bf16x8*)(wlds + (16 + kk) * 64 + lane);
      acc = __builtin_amdgcn_mfma_f32_16x16x32_bf16(pf[kk], b, acc, 0, 0, 0);
    }
  }
#pragma unroll
  for (int r = 0; r < 4; ++r) pred[wv * 256 + lane * 4 + r] = acc[r];
  __syncthreads();
  if (tid < 128) {
    int bl = tid >> 2, j = tid & 3;
    int mt2 = bl >> 4, qd = (bl & 15) >> 2, reg = bl & 3;
    const float* p0 = pred + mt2 * 256;
    const float* p1 = pred + (2 + mt2) * 256;
    int l0 = qd * 16;
    float gi = p0[(l0 + j) * 4 + reg]      + p1[(l0 + j) * 4 + reg]      + bias[j];
    float gf = p0[(l0 + 4 + j) * 4 + reg]  + p1[(l0 + 4 + j) * 4 + reg]  + bias[4 + j];
    float gg = p0[(l0 + 8 + j) * 4 + reg]  + p1[(l0 + 8 + j) * 4 + reg]  + bias[8 + j];
    float go = p0[(l0 + 12 + j) * 4 + reg] + p1[(l0 + 12 + j) * 4 + reg] + bias[12 + j];
    float c = cstate[tid & 127];
    c = sig_f(gf) * c + sig_f(gi) * tanh_f(gg);
    float h = sig_f(go) * tanh_f(c);
    cstate[tid & 127] = c;
    ((unsigned short*)st64)[tid] = (unsigned short)f2bf(h);
  }
  __syncthreads();
  if (tid < 32)
    st_dev_u64(hc + (size_t)(g * 32 + tid) * 512 + wgl * 4, st64[tid]);
}

// projection tile: 32 batch rows x 16 mel cols (n5), weights from LDS
DEV_INLINE void proj_stage(int tid, int g, int n5, const uint4* wPJ, const float* proj_b,
                           const __hip_bfloat16* h2in, float* outp, float* pred) {
  const int lane = tid & 63, wv = tid >> 6, mt = wv & 1, kh = wv >> 1;
  f32x4 acc = {0,0,0,0};
  const __hip_bfloat16* pA = h2in + (size_t)(g * 32 + mt * 16 + (lane & 15)) * 512 + kh * 256 + (lane >> 4) * 8;
#pragma unroll
  for (int kk = 0; kk < 8; ++kk) {
    bf16x8 a = ld_frag(pA + kk * 32);
    bf16x8 b = *(const bf16x8*)(wPJ + (kh * 8 + kk) * 64 + lane);
    acc = __builtin_amdgcn_mfma_f32_16x16x32_bf16(a, b, acc, 0, 0, 0);
  }
#pragma unroll
  for (int r = 0; r < 4; ++r) pred[wv * 256 + lane * 4 + r] = acc[r];
  __syncthreads();
#pragma unroll
  for (int half = 0; half < 2; ++half) {
    int gx = half * 256 + tid;            // 0..511: row*16+col
    int row = gx >> 4, col = gx & 15;
    int mt2 = row >> 4, qd = (row & 15) >> 2, reg = row & 3, ln = qd * 16 + col;
    float v = pred[mt2 * 256 + ln * 4 + reg] + pred[(2 + mt2) * 256 + ln * 4 + reg] + proj_b[n5 * 16 + col];
    outp[(size_t)(g * 32 + row) * OUTSTRIDE + n5 * 16 + col] = v;
  }
  __syncthreads();
}

__global__ __launch_bounds__(256, 1) void decoder_main(DecParams P) {
  extern __shared__ char smem[];
  uint4* wL0 = (uint4*)smem;                         // 32768 B
  uint4* wL1 = wL0 + 2048;                           // 32768
  uint4* wL2 = wL1 + 2048;                           // 32768
  uint4* wPJ = wL2 + 2048;                           // 16384
  ull*   st64 = (ull*)(wPJ + 1024);                  // 256
  float* pred = (float*)(st64 + 32);                 // 4096
  float* qls  = pred + 1024;                         // 4352 (16x68)
  float* sco  = qls + 1088;                          // 4096 (2x512)
  float* red  = sco + 1024;                          // 8192 (2x16x64)
  float* cst  = red + 2048;                          // 1536 (3x128)
  float* smx  = cst + 384;
  float* ssum = smx + 4;
  float* sinv = ssum + 4;
  int*   sbail = (int*)(sinv + 2);

  const int wg = blockIdx.x, tid = threadIdx.x;
  const int lane = tid & 63, wv = tid >> 6;
  const int g = wg >> 7;            // group 0/1 (batches g*32..g*32+31)
  const int wgl = wg & 127;         // unit slice within group
  const int fbase = g * 128;
  const int hh = wgl >> 4;          // head for attention
  const int b0g = (wgl & 15) * 2;   // group-local batch pair base
  const int bblk = b0g & ~15;       // 16-batch block for q-MFMA

  const ull t0 = __builtin_amdgcn_s_memrealtime();

  // ---- stage weights into LDS ----
  {
    const uint4* s0 = P.packL0 + (size_t)wgl * 2048;
    const uint4* s1 = P.packL1 + (size_t)wgl * 2048;
    const uint4* s2 = P.packL2 + (size_t)wgl * 2048;
    for (int i = tid; i < 2048; i += 256) { wL0[i] = s0[i]; wL1[i] = s1[i]; wL2[i] = s2[i]; }
    if (wgl < 5) { const uint4* sp = P.packP + (size_t)wgl * 1024; for (int i = tid; i < 1024; i += 256) wPJ[i] = sp[i]; }
  }
  if (tid == 0) *sbail = 0;
  if (tid < 128) { cst[tid] = 0.0f; cst[128 + tid] = 0.0f; cst[256 + tid] = 0.0f; }
  // zero activation buffers coherently (MALL holds poison otherwise)
  st_dev_u64(P.actbase + (size_t)wg * 256 + tid, 0ull);
  __syncthreads();
  publish_flag(P.flags, wg, 1u, tid);
  if (!wait_flags(P.flags, 0, 256, 1u, tid, t0, sbail)) goto bail;

  for (int t = 0; t < Tc; ++t) {
    const int cur = t & 1, pv = cur ^ 1;
    const unsigned idA = 4u * t + 1, idApub = 4u * t + 2, idBpub = 4u * t + 3,
                   idCpub = 4u * t + 4, idDpub = 4u * t + 5;
    __hip_bfloat16* h10c = P.h10b + cur * 32768; __hip_bfloat16* h10p = P.h10b + pv * 32768;
    __hip_bfloat16* h11c = P.h11b + cur * 32768; __hip_bfloat16* h11p = P.h11b + pv * 32768;
    __hip_bfloat16* h2c  = P.h2b  + cur * 32768; __hip_bfloat16* h2p  = P.h2b  + pv * 32768;
    __hip_bfloat16* ctxc = P.ctxb + cur * 32768;

    // ---- stage A: LSTM0  in=[h2p | h10p] ----
    {
      bf16x8 pf[16];
      prefetch_hi(pf, h10p, g, lane, wv);           // stale half, certified last step
      if (!wait_flags(P.flags, fbase, 128, idA, tid, t0, sbail)) goto bail;
      lstm_stage(tid, g, wgl, wL0, P.biasL0 + wgl * 16, h2p, pf, cst, h10c, pred, st64);
      publish_flag(P.flags, wg, idApub, tid);
    }
    // projection for t-1 (5 WGs/group, off the barrier path)
    if (wgl < 5 && t > 0)
      proj_stage(tid, g, wgl, wPJ, P.proj_b, h2p, P.out + (size_t)(t - 1) * MELc, pred);

    // ---- stage B: LSTM1  in=[h10c | h11p] ----
    {
      bf16x8 pf[16];
      prefetch_hi(pf, h11p, g, lane, wv);
      if (!wait_flags(P.flags, fbase, 128, idApub, tid, t0, sbail)) goto bail;
      lstm_stage(tid, g, wgl, wL1, P.biasL1 + wgl * 16, h10c, pf, cst + 128, h11c, pred, st64);
      publish_flag(P.flags, wg, idBpub, tid);
    }

    // ---- stage C: attention (2 (b,h) pairs per WG) ----
    if (!wait_flags(P.flags, fbase, 128, idBpub, tid, t0, sbail)) goto bail;
    {
      // q for the 16-batch block, this head (4 waves = 4 col tiles)
      int mrow = g * 32 + bblk + (lane & 15);
      const __hip_bfloat16* pA = h11c + (size_t)mrow * 512 + (lane >> 4) * 8;
      const uint4* pB = P.packWq + (size_t)hh * 4096 + wv * 1024;
      f32x4 acc = {0,0,0,0};
#pragma unroll
      for (int kk = 0; kk < 16; ++kk) {
        bf16x8 a = ld_frag(pA + kk * 32);
        bf16x8 b = *(const bf16x8*)(pB + kk * 64 + lane);
        acc = __builtin_amdgcn_mfma_f32_16x16x32_bf16(a, b, acc, 0, 0, 0);
      }
      int col = lane & 15, row0 = (lane >> 4) << 2;
      int dg = wv * 16 + col;
      float bq = P.attn_in_b[hh * 64 + dg];
#pragma unroll
      for (int r = 0; r < 4; ++r) qls[(row0 + r) * 68 + dg] = (acc[r] + bq) * 0.125f;
    }
    __syncthreads();
    {
      // scores: 2 pairs x 512 positions, fp8 K
      int p = tid >> 7, si = tid & 127;
      int bg = g * 32 + b0g + p;
      const float* qv = qls + ((b0g & 15) + p) * 68;
      const ull* Kb = (const ull*)(P.Kp8 + (size_t)(bg * 8 + hh) * 512 * 64);
#pragma unroll
      for (int ss = 0; ss < 4; ++ss) {
        int s = si * 4 + ss;
        const ull* kr = Kb + (size_t)s * 8;
        float acc = 0.0f;
#pragma unroll
        for (int i = 0; i < 8; ++i) {
          ull kv = kr[i];
#pragma unroll
          for (int jj = 0; jj < 8; ++jj)
            acc += qv[i * 8 + jj] * fp8tof((unsigned)(kv >> (8 * jj)) & 0xFFu);
        }
        sco[p * 512 + s] = acc;
      }
    }
    __syncthreads();
    {
      // softmax (unnormalized exp + 1/sum)
      int p = wv >> 1, half = wv & 1;
      int idx = tid & 127;
      float mx = -1e30f;
#pragma unroll
      for (int ss = 0; ss < 4; ++ss) mx = fmaxf(mx, sco[p * 512 + idx * 4 + ss]);
#pragma unroll
      for (int off = 32; off; off >>= 1) mx = fmaxf(mx, __shfl_xor(mx, off));
      if (lane == 0) smx[p * 2 + half] = mx;
      __syncthreads();
      float m = fmaxf(smx[p * 2], smx[p * 2 + 1]);
      float sum = 0.0f;
#pragma unroll
      for (int ss = 0; ss < 4; ++ss) {
        int ix = p * 512 + idx * 4 + ss;
        float e = __expf(sco[ix] - m);
        sco[ix] = e; sum += e;
      }
#pragma unroll
      for (int off = 32; off; off >>= 1) sum += __shfl_xor(sum, off);
      if (lane == 0) ssum[p * 2 + half] = sum;
      __syncthreads();
      if (tid < 2) sinv[tid] = 1.0f / (ssum[tid * 2] + ssum[tid * 2 + 1]);
    }
    __syncthreads();
    {
      // ctx = softmax . V (bf16 V, cached)
      int p = wv >> 1, half = wv & 1;
      int bg = g * 32 + b0g + p;
      int sg = lane >> 3, dj = lane & 7;
      const __hip_bfloat16* Vb = P.Vp + (size_t)(bg * 8 + hh) * 512 * 64;
      float a8[8] = {0,0,0,0,0,0,0,0};
      for (int it = 0; it < 32; ++it) {
        int s = half * 256 + it * 8 + sg;
        float w = sco[p * 512 + s];
        bf16x8 v = *(const bf16x8*)(Vb + (size_t)s * 64 + dj * 8);
#pragma unroll
        for (int e = 0; e < 8; ++e) a8[e] += w * bf2f(v[e]);
      }
      float* rp = red + ((p * 16 + half * 8 + sg) * 64) + dj * 8;
#pragma unroll
      for (int e = 0; e < 8; ++e) rp[e] = a8[e];
    }
    __syncthreads();
    if (tid < 128) {
      int p = tid >> 6, d = tid & 63;
      float sacc = 0.0f;
#pragma unroll
      for (int k = 0; k < 16; ++k) sacc += red[(p * 16 + k) * 64 + d];
      sacc *= sinv[p];
      ((unsigned short*)st64)[tid] = (unsigned short)f2bf(sacc);
    }
    __syncthreads();
    if (tid < 32) {
      int p = tid >> 4, q = tid & 15;
      st_dev_u64(ctxc + (size_t)(g * 32 + b0g + p) * 512 + hh * 64 + q * 4, st64[p * 16 + q]);
    }
    publish_flag(P.flags, wg, idCpub, tid);

    // ---- stage D: LSTM2  in=[ctxc | h2p] (out-proj folded) ----
    {
      bf16x8 pf[16];
      prefetch_hi(pf, h2p, g, lane, wv);
      if (!wait_flags(P.flags, fbase, 128, idCpub, tid, t0, sbail)) goto bail;
      lstm_stage(tid, g, wgl, wL2, P.biasL2 + wgl * 16, ctxc, pf, cst + 256, h2c, pred, st64);
      publish_flag(P.flags, wg, idDpub, tid);
    }
  }

  // final projection for t = Tc-1
  if (wgl < 5) {
    if (wait_flags(P.flags, fbase, 128, 4u * (Tc - 1) + 5, tid, t0, sbail))
      proj_stage(tid, g, wgl, wPJ, P.proj_b, P.h2b + ((Tc - 1) & 1) * 32768,
                 P.out + (size_t)(Tc - 1) * MELc, pred);
  }
  return;

bail:
  publish_flag(P.flags, wg, 0x7F000000u, tid);
}

// ---------------- launcher ----------------
extern "C" void kernel_launch(void* const* d_in, const int* in_sizes, int n_in,
                              void* d_out, int out_size, void* d_ws, size_t ws_size,
                              hipStream_t stream) {
  const float* enc        = (const float*)d_in[0];
  const float* attn_in_w  = (const float*)d_in[1];
  const float* attn_in_b  = (const float*)d_in[2];
  const float* attn_out_w = (const float*)d_in[3];
  const float* attn_out_b = (const float*)d_in[4];
  const float* w_ih0 = (const float*)d_in[5];
  const float* w_hh0 = (const float*)d_in[6];
  const float* b_ih0 = (const float*)d_in[7];
  const float* b_hh0 = (const float*)d_in[8];
  const float* w_ih1 = (const float*)d_in[9];
  const float* w_hh1 = (const float*)d_in[10];
  const float* b_ih1 = (const float*)d_in[11];
  const float* b_hh1 = (const float*)d_in[12];
  const float* w_ih2 = (const float*)d_in[13];
  const float* w_hh2 = (const float*)d_in[14];
  const float* b_ih2 = (const float*)d_in[15];
  const float* b_hh2 = (const float*)d_in[16];
  const float* proj_w = (const float*)d_in[17];
  const float* proj_b = (const float*)d_in[18];

  char* ws = (char*)d_ws;
  unsigned char*  Kp8 = (unsigned char*)(ws + OFF_KP8);
  __hip_bfloat16* Vp  = (__hip_bfloat16*)(ws + OFF_VP);
  __hip_bfloat16* pl0 = (__hip_bfloat16*)(ws + OFF_PL0);
  __hip_bfloat16* pl1 = (__hip_bfloat16*)(ws + OFF_PL1);
  __hip_bfloat16* pl2 = (__hip_bfloat16*)(ws + OFF_PL2);
  __hip_bfloat16* pwq = (__hip_bfloat16*)(ws + OFF_PWQ);
  __hip_bfloat16* pp  = (__hip_bfloat16*)(ws + OFF_PP);
  float* bl0 = (float*)(ws + OFF_BL0);
  float* bl1 = (float*)(ws + OFF_BL1);
  float* bl2 = (float*)(ws + OFF_BL2);
  float* b2e = (float*)(ws + OFF_B2E);
  __hip_bfloat16* w2e = (__hip_bfloat16*)(ws + OFF_W2E);
  float* wot = (float*)(ws + OFF_WOT);
  char* act  = ws + OFF_ACT;
  unsigned* flags = (unsigned*)(ws + OFF_FLG);

  hipMemsetAsync(flags, 0, 4096, stream);

  // K (fp8 e4m3) and V (bf16), packed [b][h][s][d]
  gemm_setup<<<dim3(8, 512), 256, 0, stream>>>(enc, attn_in_w + 512 * 512, attn_in_b + 512, nullptr, Kp8, 2);
  gemm_setup<<<dim3(8, 512), 256, 0, stream>>>(enc, attn_in_w + 1024 * 512, attn_in_b + 1024, Vp, nullptr, 0);
  // W2eff = W2ih @ Wout
  transpose512<<<dim3(16, 16), 256, 0, stream>>>(attn_out_w, wot);
  gemm_setup<<<dim3(8, 32), 256, 0, stream>>>(w_ih2, wot, nullptr, w2e, nullptr, 1);
  b2eff_k<<<8, 256, 0, stream>>>(w_ih2, attn_out_b, b_ih2, b_hh2, b2e);
  // fragment packing
  pack_lstm<<<128, 256, 0, stream>>>(w_ih0, nullptr, w_hh0, b_ih0, b_hh0, nullptr, pl0, bl0, 0);
  pack_lstm<<<128, 256, 0, stream>>>(w_ih1, nullptr, w_hh1, b_ih1, b_hh1, nullptr, pl1, bl1, 0);
  pack_lstm<<<128, 256, 0, stream>>>(nullptr, w2e, w_hh2, nullptr, nullptr, b2e, pl2, bl2, 1);
  pack_wq<<<8, 256, 0, stream>>>(attn_in_w, pwq);
  pack_proj<<<5, 256, 0, stream>>>(proj_w, pp);

  DecParams p;
  p.attn_in_b = attn_in_b;
  p.proj_b = proj_b;
  p.packL0 = (const uint4*)pl0; p.packL1 = (const uint4*)pl1; p.packL2 = (const uint4*)pl2;
  p.biasL0 = bl0; p.biasL1 = bl1; p.biasL2 = bl2;
  p.packWq = (const uint4*)pwq; p.packP = (const uint4*)pp;
  p.Kp8 = Kp8; p.Vp = Vp;
  p.h10b = (__hip_bfloat16*)(act + 0);
  p.h11b = (__hip_bfloat16*)(act + 131072);
  p.h2b  = (__hip_bfloat16*)(act + 262144);
  p.ctxb = (__hip_bfloat16*)(act + 393216);
  p.actbase = (ull*)act;
  p.flags = flags;
  p.out = (float*)d_out;

  // allow >64KB dynamic LDS (no-op if unsupported)
  (void)hipFuncSetAttribute((const void*)decoder_main,
                            hipFuncAttributeMaxDynamicSharedMemorySize, DYN_LDS);
  decoder_main<<<dim3(256), dim3(256), DYN_LDS, stream>>>(p);
}